// Round 10
// baseline (132.947 us; speedup 1.0000x reference)
//
#include <hip/hip_runtime.h>
#include <math.h>

#define HH 512
#define WW 512
#define HB 64       // band height (8 bands per plane -> grid 992)
#define NR4 528     // float4 elems per row: 8 left pad + 512 + 8 right pad
#define PADL 8      // pad so halo stays inside swizzle blocks
#define KR 8        // output rows per group (32 vertical accumulators)

// R9 -> R10: KR 4->8 with 8-column H-coarsening.
//  - LDS reads: 18 b128 taps per 8 points = 2.25/pt (was 3.5/pt) -> -36%
//  - vertical global loads: 18 rows per 8 output rows (was 14 per 4)
//  - barriers halved (8 groups/band instead of 16)
//  - LDS 67.6 KB -> 2 blocks/CU; 16 waves/CU is enough TLP (R7-R9)
// Register discipline (R1-R6 lesson: spill = death): sched_barrier(0) fences
// every ~6 taps cap in-flight LDS/global loads; watch WRITE_SIZE ~0 as the
// no-spill tripwire.

__device__ __forceinline__ int swz(int u) { return u ^ ((u >> 3) & 7); }

__global__ __launch_bounds__(512, 1)
void ssim_main(const float* __restrict__ Pg, const float* __restrict__ Tg,
               float* __restrict__ partial) {
  __shared__ __align__(16) float4 S4[KR][NR4];
  __shared__ float wsum[8];

  const int tid = threadIdx.x;            // vertical pass: column 0..511
  const int blk = blockIdx.x;
  const int plane = blk >> 3;
  const int band  = blk & 7;
  const int o0 = band * HB;               // first output row of band
  const float* __restrict__ P = Pg + (size_t)plane * (HH * WW);
  const float* __restrict__ T = Tg + (size_t)plane * (HH * WW);

  // zero LDS once: halo pads (u<8, u>=520) must be 0 and are never rewritten;
  // interior u in [8,520) is fully overwritten every group (swz bijects each
  // aligned 8-block onto itself).
  {
    float4* base = &S4[0][0];
    const float4 z = make_float4(0.f, 0.f, 0.f, 0.f);
    for (int idx = tid; idx < KR * NR4; idx += 512) base[idx] = z;
  }

  // Gaussian weights, computed in double then rounded to f32 (matches jnp f32)
  float w[11];
  {
    double g[11], s = 0.0;
#pragma unroll
    for (int k = 0; k < 11; ++k) {
      double c = (double)(k - 5);
      g[k] = exp(-c * c / 4.5);
      s += g[k];
    }
#pragma unroll
    for (int k = 0; k < 11; ++k)
      w[k] = __uint_as_float(__builtin_amdgcn_readfirstlane(
                 __float_as_uint((float)(g[k] / s))));
  }

  float sum = 0.f;
  const int jr = tid >> 6;                // H-pass: row within group (0..7)
  const int q  = tid & 63;                // H-pass: 8-col block (cols 8q..8q+7)

  for (int g = 0; g < HB; g += KR) {      // 8 groups of 8 output rows
    // ---- vertical pass: stream 18 input rows, 32 accumulators ----
    float mp[KR], mt[KR], s2[KR], sc[KR];
#pragma unroll
    for (int j = 0; j < KR; ++j) { mp[j] = 0.f; mt[j] = 0.f; s2[j] = 0.f; sc[j] = 0.f; }
    const int rbase = o0 + g - 5;         // input row of ri=0 (may be <0)
#pragma unroll
    for (int ri = 0; ri < KR + 10; ++ri) {
      const int r_in = rbase + ri;
      const bool v = (r_in >= 0) && (r_in < HH);
      const float p = v ? P[(size_t)r_in * WW + tid] : 0.f;
      const float t = v ? T[(size_t)r_in * WW + tid] : 0.f;
      const float q2 = fmaf(t, t, p * p);
      const float q3 = p * t;
#pragma unroll
      for (int j = 0; j < KR; ++j) {
        if (ri - j >= 0 && ri - j <= 10) {     // compile-time per (ri,j)
          const float wk = w[ri - j];
          mp[j] = fmaf(wk, p,  mp[j]);
          mt[j] = fmaf(wk, t,  mt[j]);
          s2[j] = fmaf(wk, q2, s2[j]);
          sc[j] = fmaf(wk, q3, sc[j]);
        }
      }
      if (ri == 5 || ri == 11) __builtin_amdgcn_sched_barrier(0);
    }

    // ---- stage group tile (field-packed float4, swizzled) ----
    __syncthreads();                      // prior group's readers are done
#pragma unroll
    for (int j = 0; j < KR; ++j)
      S4[j][swz(PADL + tid)] = make_float4(mp[j], mt[j], s2[j], sc[j]);
    __syncthreads();

    // ---- horizontal pass + SSIM: 8 columns per thread, 18 taps ----
    float hp[8], ht[8], h2[8], hc[8];
#pragma unroll
    for (int m = 0; m < 8; ++m) { hp[m] = 0.f; ht[m] = 0.f; h2[m] = 0.f; hc[m] = 0.f; }
#pragma unroll
    for (int k = 0; k < 18; ++k) {
      // tap column = 8q - 5 + k  ->  u = PADL + 8q - 5 + k = 8q + 3 + k
      const float4 v4 = S4[jr][swz(8 * q + 3 + k)];
#pragma unroll
      for (int m = 0; m < 8; ++m) {
        if (k - m >= 0 && k - m <= 10) {       // compile-time per (k,m)
          const float wk = w[k - m];
          hp[m] = fmaf(wk, v4.x, hp[m]);
          ht[m] = fmaf(wk, v4.y, ht[m]);
          h2[m] = fmaf(wk, v4.z, h2[m]);
          hc[m] = fmaf(wk, v4.w, hc[m]);
        }
      }
      if (k == 5 || k == 11) __builtin_amdgcn_sched_barrier(0);
    }
#pragma unroll
    for (int m = 0; m < 8; ++m) {
      const float hmp = hp[m], hmt = ht[m];
      const float mp2 = hmp * hmp, mt2 = hmt * hmt, mct = hmp * hmt;
      const float ssum = fmaxf(h2[m] - mp2 - mt2, 0.f);
      const float scv = hc[m] - mct;
      const float num = fmaf(2.f, mct, 1.0e-4f) * fmaf(2.f, scv, 9.0e-4f);
      const float den = (mp2 + mt2 + 1.0e-4f) * (ssum + 9.0e-4f);
      sum += num * __builtin_amdgcn_rcpf(den);
    }
  }

  // block reduction of ssim partial sum
#pragma unroll
  for (int off = 32; off > 0; off >>= 1) sum += __shfl_down(sum, off, 64);
  if ((tid & 63) == 0) wsum[tid >> 6] = sum;
  __syncthreads();
  if (tid == 0) {
    float s = 0.f;
#pragma unroll
    for (int k2 = 0; k2 < 8; ++k2) s += wsum[k2];
    partial[blk] = s;
  }
}

__global__ void ssim_fin(const float* __restrict__ partial,
                         float* __restrict__ out, int n) {
  __shared__ double ws[4];
  double s = 0.0;
  for (int idx = threadIdx.x; idx < n; idx += 256) s += (double)partial[idx];
#pragma unroll
  for (int off = 32; off > 0; off >>= 1) s += __shfl_down(s, off, 64);
  if ((threadIdx.x & 63) == 0) ws[threadIdx.x >> 6] = s;
  __syncthreads();
  if (threadIdx.x == 0) {
    double tt = ws[0] + ws[1] + ws[2] + ws[3];
    out[0] = (float)(1.0 - tt / 32505856.0);
  }
}

extern "C" void kernel_launch(void* const* d_in, const int* in_sizes, int n_in,
                              void* d_out, int out_size, void* d_ws, size_t ws_size,
                              hipStream_t stream) {
  const float* pred = (const float*)d_in[0];
  const float* tgt  = (const float*)d_in[1];
  float* out        = (float*)d_out;
  float* partial    = (float*)d_ws;   // 992 floats of scratch

  ssim_main<<<dim3(992), dim3(512), 0, stream>>>(pred, tgt, partial);
  ssim_fin<<<dim3(1), dim3(256), 0, stream>>>(partial, out, 992);
}

// Round 11
// 112.488 us; speedup vs baseline: 1.1819x; 1.1819x over previous
//
#include <hip/hip_runtime.h>
#include <math.h>

#define HH 512
#define WW 512
#define HB 64       // band height (8 bands per plane -> grid 992)
#define KR 4        // output rows per group
#define SUB 138     // float4 slots per sub-array; 138%8==2 -> conflict-free
                    // writes (8-lane phase hits all 8 bank-quads) and >=132
                    // slots (128 cols + 2 halo each side)
#define ROWF4 (4 * SUB)   // 552 float4 per row

// R11: R9 structure (KR=4, M=4, 35KB LDS) with three fixes from the R9/R10
// post-mortems (R9: VALU-issue 77us >> 48us of FMAs -> overhead-bound; 7.1M
// LDS conflict cycles; R10's KR=8 killed occupancy):
//  1. transposed sub-array LDS (c -> sub=c&3, slot=c>>2): all 14 H-taps are
//     ds_read_b128 at COMPILE-TIME offsets from one base (no per-tap VALU),
//     lane stride 16B -> conflict-free reads; stride-138 writes conflict-free.
//  2. packed f32 FMA via ext_vector_type(2) + __builtin_elementwise_fma:
//     {mu_p,mu_t} and {s2,sc} pairs -> v_pk_fma_f32, halving FMA issue.
//  3. wave-uniform boundary fast path: 13/16 groups skip per-row range checks.

typedef float v2f __attribute__((ext_vector_type(2)));

__global__ __launch_bounds__(512, 1)
void ssim_main(const float* __restrict__ Pg, const float* __restrict__ Tg,
               float* __restrict__ partial) {
  __shared__ __align__(16) float4 S4[KR * ROWF4];   // 35328 B
  __shared__ float wsum[8];

  const int tid = threadIdx.x;            // vertical pass: column 0..511
  const int blk = blockIdx.x;
  const int plane = blk >> 3;
  const int band  = blk & 7;
  const int o0 = band * HB;               // first output row of band
  const float* __restrict__ P = Pg + (size_t)plane * (HH * WW);
  const float* __restrict__ T = Tg + (size_t)plane * (HH * WW);

  // zero LDS once: halo slots (0,1 and 130..137 of each sub-array) must stay
  // 0 forever; interior slots 2..129 are fully overwritten every group.
  {
    const float4 z = make_float4(0.f, 0.f, 0.f, 0.f);
    for (int idx = tid; idx < KR * ROWF4; idx += 512) S4[idx] = z;
  }

  // Gaussian weights, computed in double then rounded to f32 (matches jnp f32)
  float w[11];
  {
    double g[11], s = 0.0;
#pragma unroll
    for (int k = 0; k < 11; ++k) {
      double c = (double)(k - 5);
      g[k] = exp(-c * c / 4.5);
      s += g[k];
    }
#pragma unroll
    for (int k = 0; k < 11; ++k)
      w[k] = __uint_as_float(__builtin_amdgcn_readfirstlane(
                 __float_as_uint((float)(g[k] / s))));
  }

  float sum = 0.f;
  const int jr = tid >> 7;                // H-pass: row within group (0..3)
  const int q  = tid & 127;               // H-pass: 4-col block (cols 4q..4q+3)
  // per-thread fixed LDS bases (hoisted; all tap/write offsets are immediates)
  float4* const rdbase = &S4[jr * ROWF4 + q + 2];
  float4* const wrbase = &S4[(tid & 3) * SUB + (tid >> 2) + 2];

  for (int g = 0; g < HB; g += KR) {      // 16 groups of 4 output rows
    // ---- vertical pass: stream 14 input rows, packed accumulators ----
    v2f apt[KR], asq[KR];
    {
      const v2f z = {0.f, 0.f};
#pragma unroll
      for (int j = 0; j < KR; ++j) { apt[j] = z; asq[j] = z; }
    }
    const int rbase = o0 + g - 5;         // input row of ri=0 (may be <0)

#define VACC(RI, PV, TV) {                                                 \
      const float p_ = (PV), t_ = (TV);                                   \
      const v2f pt  = {p_, t_};                                           \
      const v2f q23 = {fmaf(t_, t_, p_ * p_), p_ * t_};                   \
      _Pragma("unroll")                                                   \
      for (int j = 0; j < KR; ++j) {                                      \
        if ((RI) - j >= 0 && (RI) - j <= 10) {                            \
          const float wk = w[(RI) - j];                                   \
          const v2f wv = {wk, wk};                                        \
          apt[j] = __builtin_elementwise_fma(wv, pt,  apt[j]);            \
          asq[j] = __builtin_elementwise_fma(wv, q23, asq[j]);            \
        }                                                                 \
      }                                                                   \
    }

    if (rbase >= 0 && rbase + 13 < HH) {
      // fast path: all 14 rows in range, no per-row guards
      const float* const Pr = P + (size_t)rbase * WW + tid;
      const float* const Tr = T + (size_t)rbase * WW + tid;
#pragma unroll
      for (int ri = 0; ri < KR + 10; ++ri) {
        VACC(ri, Pr[ri * WW], Tr[ri * WW]);
        if (ri == 6) __builtin_amdgcn_sched_barrier(0);
      }
    } else {
      // edge groups (3 instances per plane): guarded loads
#pragma unroll
      for (int ri = 0; ri < KR + 10; ++ri) {
        const int r_in = rbase + ri;
        const bool v = (r_in >= 0) && (r_in < HH);
        const float p = v ? P[(size_t)r_in * WW + tid] : 0.f;
        const float t = v ? T[(size_t)r_in * WW + tid] : 0.f;
        VACC(ri, p, t);
        if (ri == 6) __builtin_amdgcn_sched_barrier(0);
      }
    }
#undef VACC

    // ---- stage group tile (transposed sub-array layout) ----
    __syncthreads();                      // prior group's readers are done
#pragma unroll
    for (int j = 0; j < KR; ++j)
      wrbase[j * ROWF4] = make_float4(apt[j][0], apt[j][1], asq[j][0], asq[j][1]);
    __syncthreads();

    // ---- horizontal pass + SSIM: 4 cols/thread, 14 imm-offset taps ----
    v2f hpt[4], hsq[4];
    {
      const v2f z = {0.f, 0.f};
#pragma unroll
      for (int m = 0; m < 4; ++m) { hpt[m] = z; hsq[m] = z; }
    }
#pragma unroll
    for (int k = 0; k < 14; ++k) {
      const int d = k - 5;                 // tap col = 4q + d
      const int s = d & 3;                 // sub-array
      const int o = (d - s) >> 2;          // slot offset (floor(d/4))
      const float4 v4 = rdbase[s * SUB + o];
      const v2f lo = {v4.x, v4.y};
      const v2f hi = {v4.z, v4.w};
#pragma unroll
      for (int m = 0; m < 4; ++m) {
        if (k - m >= 0 && k - m <= 10) {   // compile-time per (k,m)
          const float wk = w[k - m];
          const v2f wv = {wk, wk};
          hpt[m] = __builtin_elementwise_fma(wv, lo, hpt[m]);
          hsq[m] = __builtin_elementwise_fma(wv, hi, hsq[m]);
        }
      }
      if (k == 6) __builtin_amdgcn_sched_barrier(0);
    }
#pragma unroll
    for (int m = 0; m < 4; ++m) {
      const float hmp = hpt[m][0], hmt = hpt[m][1];
      const float mp2 = hmp * hmp, mt2 = hmt * hmt, mct = hmp * hmt;
      const float ssum = fmaxf(hsq[m][0] - mp2 - mt2, 0.f);
      const float scv = hsq[m][1] - mct;
      const float num = fmaf(2.f, mct, 1.0e-4f) * fmaf(2.f, scv, 9.0e-4f);
      const float den = (mp2 + mt2 + 1.0e-4f) * (ssum + 9.0e-4f);
      sum += num * __builtin_amdgcn_rcpf(den);
    }
  }

  // block reduction of ssim partial sum
#pragma unroll
  for (int off = 32; off > 0; off >>= 1) sum += __shfl_down(sum, off, 64);
  if ((tid & 63) == 0) wsum[tid >> 6] = sum;
  __syncthreads();
  if (tid == 0) {
    float s = 0.f;
#pragma unroll
    for (int k2 = 0; k2 < 8; ++k2) s += wsum[k2];
    partial[blk] = s;
  }
}

__global__ void ssim_fin(const float* __restrict__ partial,
                         float* __restrict__ out, int n) {
  __shared__ double ws[4];
  double s = 0.0;
  for (int idx = threadIdx.x; idx < n; idx += 256) s += (double)partial[idx];
#pragma unroll
  for (int off = 32; off > 0; off >>= 1) s += __shfl_down(s, off, 64);
  if ((threadIdx.x & 63) == 0) ws[threadIdx.x >> 6] = s;
  __syncthreads();
  if (threadIdx.x == 0) {
    double tt = ws[0] + ws[1] + ws[2] + ws[3];
    out[0] = (float)(1.0 - tt / 32505856.0);
  }
}

extern "C" void kernel_launch(void* const* d_in, const int* in_sizes, int n_in,
                              void* d_out, int out_size, void* d_ws, size_t ws_size,
                              hipStream_t stream) {
  const float* pred = (const float*)d_in[0];
  const float* tgt  = (const float*)d_in[1];
  float* out        = (float*)d_out;
  float* partial    = (float*)d_ws;   // 992 floats of scratch

  ssim_main<<<dim3(992), dim3(512), 0, stream>>>(pred, tgt, partial);
  ssim_fin<<<dim3(1), dim3(256), 0, stream>>>(partial, out, 992);
}

// Round 12
// 101.331 us; speedup vs baseline: 1.3120x; 1.1101x over previous
//
#include <hip/hip_runtime.h>
#include <math.h>

#define HH 512
#define WW 512
#define HB 64       // band height (8 bands per plane -> grid 992)
#define KR 4        // output rows per group
#define SUB 138     // float4 slots per sub-array; 138%8==2 -> conflict-free
#define ROWF4 (4 * SUB)   // 552 float4 per row

// R12: R11's verified layout (conflicts=0, imm-offset taps) + latency attack:
//  1. register ring pr/tr[10] (rows rbase..rbase+9) with shift-4 rotation;
//     only 4 NEW rows prefetched per group, issued one group early ->
//     ~500cy latency budget, loads/group 28->8, no per-row guards.
//  2. light barriers: s_waitcnt lgkmcnt(0) + raw s_barrier instead of
//     __syncthreads() -- __syncthreads drains vmcnt(0), which would kill
//     the prefetch overlap (m97 barrier-drain effect). LDS visibility only
//     needs lgkmcnt.
//  3. peak live ~80-95 VGPR < 128 cap. Tripwire: WRITE_SIZE must stay ~0.

typedef float v2f __attribute__((ext_vector_type(2)));

__device__ __forceinline__ void bar_lgkm() {
  asm volatile("s_waitcnt lgkmcnt(0)" ::: "memory");
  __builtin_amdgcn_s_barrier();
  __builtin_amdgcn_sched_barrier(0);
}

__global__ __launch_bounds__(512, 1)
void ssim_main(const float* __restrict__ Pg, const float* __restrict__ Tg,
               float* __restrict__ partial) {
  __shared__ __align__(16) float4 S4[KR * ROWF4];   // 35328 B
  __shared__ float wsum[8];

  const int tid = threadIdx.x;            // vertical pass: column 0..511
  const int blk = blockIdx.x;
  const int plane = blk >> 3;
  const int band  = blk & 7;
  const int o0 = band * HB;               // first output row of band
  const float* __restrict__ P = Pg + (size_t)plane * (HH * WW);
  const float* __restrict__ T = Tg + (size_t)plane * (HH * WW);

  // zero LDS once: halo slots (0,1 and 130..137 of each sub-array) must stay
  // 0 forever; interior slots 2..129 are fully overwritten every group.
  {
    const float4 z = make_float4(0.f, 0.f, 0.f, 0.f);
    for (int idx = tid; idx < KR * ROWF4; idx += 512) S4[idx] = z;
  }

  // Gaussian weights, computed in double then rounded to f32 (matches jnp f32)
  float w[11];
  {
    double g[11], s = 0.0;
#pragma unroll
    for (int k = 0; k < 11; ++k) {
      double c = (double)(k - 5);
      g[k] = exp(-c * c / 4.5);
      s += g[k];
    }
#pragma unroll
    for (int k = 0; k < 11; ++k)
      w[k] = __uint_as_float(__builtin_amdgcn_readfirstlane(
                 __float_as_uint((float)(g[k] / s))));
  }

  float sum = 0.f;
  const int jr = tid >> 7;                // H-pass: row within group (0..3)
  const int q  = tid & 127;               // H-pass: 4-col block (cols 4q..4q+3)
  // per-thread fixed LDS bases (all tap/write offsets are immediates)
  float4* const rdbase = &S4[jr * ROWF4 + q + 2];
  float4* const wrbase = &S4[(tid & 3) * SUB + (tid >> 2) + 2];

  // ---- register ring: pr/tr[i] = input row rbase+i (i=0..9); pn/tn = rows
  // rbase+10..13 in flight. rbase = o0 + g - 5.
  float pr[10], tr[10], pn[4], tn[4];
#pragma unroll
  for (int i = 0; i < 10; ++i) {
    const int r = o0 - 5 + i;
    const bool v = (r >= 0);              // r <= o0+4 <= 452 < HH always
    pr[i] = v ? P[(size_t)r * WW + tid] : 0.f;
    tr[i] = v ? T[(size_t)r * WW + tid] : 0.f;
  }
#pragma unroll
  for (int i = 0; i < 4; ++i) {
    const int r = o0 + 5 + i;             // always in [5, 461]
    pn[i] = P[(size_t)r * WW + tid];
    tn[i] = T[(size_t)r * WW + tid];
  }

  for (int g = 0; g < HB; g += KR) {      // 16 groups of 4 output rows
    // ---- vertical pass: pure register math, packed accumulators ----
    v2f apt[KR], asq[KR];
    {
      const v2f z = {0.f, 0.f};
#pragma unroll
      for (int j = 0; j < KR; ++j) { apt[j] = z; asq[j] = z; }
    }

#define VACC(RI, PV, TV) {                                                 \
      const float p_ = (PV), t_ = (TV);                                   \
      const v2f pt  = {p_, t_};                                           \
      const v2f q23 = {fmaf(t_, t_, p_ * p_), p_ * t_};                   \
      _Pragma("unroll")                                                   \
      for (int j = 0; j < KR; ++j) {                                      \
        if ((RI) - j >= 0 && (RI) - j <= 10) {                            \
          const float wk = w[(RI) - j];                                   \
          const v2f wv = {wk, wk};                                        \
          apt[j] = __builtin_elementwise_fma(wv, pt,  apt[j]);            \
          asq[j] = __builtin_elementwise_fma(wv, q23, asq[j]);            \
        }                                                                 \
      }                                                                   \
    }

#pragma unroll
    for (int ri = 0; ri < 10; ++ri) VACC(ri, pr[ri], tr[ri]);
#pragma unroll
    for (int i = 0; i < 4; ++i) VACC(10 + i, pn[i], tn[i]);
#undef VACC

    // ---- rotate ring by 4, then issue next group's 4-row prefetch ----
#pragma unroll
    for (int i = 0; i < 6; ++i) { pr[i] = pr[i + 4]; tr[i] = tr[i + 4]; }
#pragma unroll
    for (int i = 0; i < 4; ++i) { pr[6 + i] = pn[i]; tr[6 + i] = tn[i]; }
#pragma unroll
    for (int i = 0; i < 4; ++i) {
      // next group's rows rbase'+10..13 = o0+g+9..12 (>=9; may exceed HH-1)
      const int r = o0 + g + 9 + i;
      if (r < HH) {
        pn[i] = P[(size_t)r * WW + tid];
        tn[i] = T[(size_t)r * WW + tid];
      } else {
        pn[i] = 0.f; tn[i] = 0.f;
      }
    }

    // ---- stage group tile (loads stay in flight: no vmcnt drain) ----
    bar_lgkm();                           // prev H-pass readers done
#pragma unroll
    for (int j = 0; j < KR; ++j)
      wrbase[j * ROWF4] = make_float4(apt[j][0], apt[j][1], asq[j][0], asq[j][1]);
    bar_lgkm();                           // writes visible to all waves

    // ---- horizontal pass + SSIM: 4 cols/thread, 14 imm-offset taps ----
    v2f hpt[4], hsq[4];
    {
      const v2f z = {0.f, 0.f};
#pragma unroll
      for (int m = 0; m < 4; ++m) { hpt[m] = z; hsq[m] = z; }
    }
#pragma unroll
    for (int k = 0; k < 14; ++k) {
      const int d = k - 5;                 // tap col = 4q + d
      const int s = d & 3;                 // sub-array
      const int o = (d - s) >> 2;          // slot offset (floor(d/4))
      const float4 v4 = rdbase[s * SUB + o];
      const v2f lo = {v4.x, v4.y};
      const v2f hi = {v4.z, v4.w};
#pragma unroll
      for (int m = 0; m < 4; ++m) {
        if (k - m >= 0 && k - m <= 10) {   // compile-time per (k,m)
          const float wk = w[k - m];
          const v2f wv = {wk, wk};
          hpt[m] = __builtin_elementwise_fma(wv, lo, hpt[m]);
          hsq[m] = __builtin_elementwise_fma(wv, hi, hsq[m]);
        }
      }
      if (k == 6) __builtin_amdgcn_sched_barrier(0);  // cap in-flight taps
    }
#pragma unroll
    for (int m = 0; m < 4; ++m) {
      const float hmp = hpt[m][0], hmt = hpt[m][1];
      const float mp2 = hmp * hmp, mt2 = hmt * hmt, mct = hmp * hmt;
      const float ssum = fmaxf(hsq[m][0] - mp2 - mt2, 0.f);
      const float scv = hsq[m][1] - mct;
      const float num = fmaf(2.f, mct, 1.0e-4f) * fmaf(2.f, scv, 9.0e-4f);
      const float den = (mp2 + mt2 + 1.0e-4f) * (ssum + 9.0e-4f);
      sum += num * __builtin_amdgcn_rcpf(den);
    }
  }

  // block reduction of ssim partial sum
#pragma unroll
  for (int off = 32; off > 0; off >>= 1) sum += __shfl_down(sum, off, 64);
  if ((tid & 63) == 0) wsum[tid >> 6] = sum;
  __syncthreads();
  if (tid == 0) {
    float s = 0.f;
#pragma unroll
    for (int k2 = 0; k2 < 8; ++k2) s += wsum[k2];
    partial[blk] = s;
  }
}

__global__ void ssim_fin(const float* __restrict__ partial,
                         float* __restrict__ out, int n) {
  __shared__ double ws[4];
  double s = 0.0;
  for (int idx = threadIdx.x; idx < n; idx += 256) s += (double)partial[idx];
#pragma unroll
  for (int off = 32; off > 0; off >>= 1) s += __shfl_down(s, off, 64);
  if ((threadIdx.x & 63) == 0) ws[threadIdx.x >> 6] = s;
  __syncthreads();
  if (threadIdx.x == 0) {
    double tt = ws[0] + ws[1] + ws[2] + ws[3];
    out[0] = (float)(1.0 - tt / 32505856.0);
  }
}

extern "C" void kernel_launch(void* const* d_in, const int* in_sizes, int n_in,
                              void* d_out, int out_size, void* d_ws, size_t ws_size,
                              hipStream_t stream) {
  const float* pred = (const float*)d_in[0];
  const float* tgt  = (const float*)d_in[1];
  float* out        = (float*)d_out;
  float* partial    = (float*)d_ws;   // 992 floats of scratch

  ssim_main<<<dim3(992), dim3(512), 0, stream>>>(pred, tgt, partial);
  ssim_fin<<<dim3(1), dim3(256), 0, stream>>>(partial, out, 992);
}